// Round 12
// baseline (43859.079 us; speedup 1.0000x reference)
//
#include <hip/hip_runtime.h>
#include <math.h>

#define NB 8192
enum { ACT_NONE = 0, ACT_RELU = 1, ACT_TANH = 2 };

typedef double d4_t __attribute__((ext_vector_type(4)));

struct GSet {            // gathered-message A-segment: relu(T[idx]+bT), 256 wide
    const float* T;
    const float* bT;
    const int*   idx;
    int is, io;          // id = idx[b*is + io]
};

// ---------------------------------------------------------------------------
// f64 MFMA GEMM, r8 tile (BK=16, zero-conflict staging). NS = number of
// gathered 256-wide A-segments appended after KA head columns (templated so
// NS=0 compiles to the branch-free r8 body).
// ---------------------------------------------------------------------------
template<typename TA, int ACT, bool HB, bool HA, int NS>
__global__ __launch_bounds__(256)
void mgemm3(const TA* __restrict__ A, int lda, int KA,
            const float* __restrict__ W,
            const float* __restrict__ bias,
            const double* __restrict__ addsrc,
            double* __restrict__ C, int K,
            GSet g0, GSet g1)
{
    __shared__ double Al[16][129];
    __shared__ double Bl[16][128];
    __shared__ int idc[2][128];
    const int tid  = threadIdx.x;
    const int lane = tid & 63;
    const int w    = tid >> 6;
    const int q    = lane >> 4;
    const int c    = lane & 15;
    const int m0w  = (w >> 1) * 64;
    const int n0w  = (w & 1) * 64;
    const size_t m0 = (size_t)blockIdx.y * 128;
    const int    n0 = blockIdx.x * 128;

    const int srow = tid >> 1;
    const int half = tid & 1;
    const int bk   = tid >> 4;
    const int bseg = tid & 15;

    if (NS > 0 && tid < 128)
        idc[0][tid] = g0.idx[(size_t)(m0 + tid) * g0.is + g0.io];
    if (NS > 1 && tid >= 128)
        idc[1][tid - 128] = g1.idx[(size_t)(m0 + tid - 128) * g1.is + g1.io];

    d4_t acc[4][4];
#pragma unroll
    for (int i = 0; i < 4; i++)
#pragma unroll
        for (int j = 0; j < 4; j++) acc[i][j] = (d4_t){0.0, 0.0, 0.0, 0.0};

    if (NS > 0) __syncthreads();

    for (int kt = 0; kt < K; kt += 16) {
        if (NS == 0) {
            const TA* ap = A + (m0 + srow) * (size_t)lda + kt + half * 8;
#pragma unroll
            for (int e = 0; e < 8; e++)
                Al[half * 8 + e][srow] = (double)ap[e];
        } else {
            const int kb = kt + half * 8;
            if (kb < KA) {
                const TA* ap = A + (m0 + srow) * (size_t)lda + kb;
#pragma unroll
                for (int e = 0; e < 8; e++)
                    Al[half * 8 + e][srow] = (double)ap[e];
            } else {
                const int koff = kb - KA;
                const int s = koff >> 8;
                const int lk = koff & 255;
                const GSet& g = s ? g1 : g0;
                const float* tp = g.T + (size_t)idc[s][srow] * 256 + lk;
                const float* bp = g.bT + lk;
#pragma unroll
                for (int e = 0; e < 8; e++) {
                    double v = (double)tp[e] + (double)bp[e];
                    Al[half * 8 + e][srow] = v > 0.0 ? v : 0.0;
                }
            }
        }
        {
            const float* wp = W + (size_t)(kt + bk) * 1024 + n0 + bseg;
#pragma unroll
            for (int e = 0; e < 8; e++)
                Bl[bk][bseg + 16 * e] = (double)wp[16 * e];
        }
        __syncthreads();
#pragma unroll
        for (int kk = 0; kk < 4; kk++) {
            double a[4], b[4];
#pragma unroll
            for (int i = 0; i < 4; i++) a[i] = Al[kk * 4 + q][m0w + i * 16 + c];
#pragma unroll
            for (int j = 0; j < 4; j++) b[j] = Bl[kk * 4 + q][n0w + j * 16 + c];
#pragma unroll
            for (int i = 0; i < 4; i++)
#pragma unroll
                for (int j = 0; j < 4; j++)
                    acc[i][j] = __builtin_amdgcn_mfma_f64_16x16x4f64(
                        a[i], b[j], acc[i][j], 0, 0, 0);
        }
        __syncthreads();
    }

#pragma unroll
    for (int i = 0; i < 4; i++)
#pragma unroll
        for (int j = 0; j < 4; j++)
#pragma unroll
            for (int v = 0; v < 4; v++) {
                size_t gr = m0 + m0w + i * 16 + q * 4 + v;
                int    gc = n0 + n0w + j * 16 + c;
                double val = acc[i][j][v];
                if (HB) val += (double)bias[gc];
                if (HA) val += addsrc[gr * 1024 + gc];
                if (ACT == ACT_RELU) val = val > 0.0 ? val : 0.0;
                if (ACT == ACT_TANH) val = tanh(val);
                C[gr * 1024 + gc] = val;
            }
}

// ---------------------------------------------------------------------------
// Fused Wo-GEMV + f64 softmax + f32-quantized stable top-k (regular kernel).
// ---------------------------------------------------------------------------
__global__ __launch_bounds__(256)
void wo_topk(const double* __restrict__ h2,
             const float* __restrict__ W, const float* __restrict__ bo,
             int N, int k,
             float* __restrict__ sout, int* __restrict__ iout,
             int stride, int soff)
{
    __shared__ double h2s[8][1024];
    __shared__ double dred[256];
    __shared__ float  pred[256];
    __shared__ int    ired[256];
    const int tid = threadIdx.x;
    const size_t rbase = (size_t)blockIdx.x * 8;

    for (int t = tid; t < 8192; t += 256)
        h2s[t >> 10][t & 1023] = h2[(rbase + (t >> 10)) * 1024 + (t & 1023)];
    __syncthreads();

    const int c = tid;
    double a[8] = {0, 0, 0, 0, 0, 0, 0, 0};
    if (c < N) {
        for (int kk = 0; kk < 1024; kk++) {
            double wv = (double)W[(size_t)kk * N + c];
#pragma unroll
            for (int r = 0; r < 8; r++)
                a[r] = fma(h2s[r][kk], wv, a[r]);
        }
    }
    double bb = (c < N) ? (double)bo[c] : 0.0;

    for (int r = 0; r < 8; r++) {
        size_t b = rbase + r;
        double lgv = a[r] + bb;
        dred[tid] = (c < N) ? lgv : -INFINITY;
        __syncthreads();
        for (int s = 128; s; s >>= 1) {
            if (tid < s) dred[tid] = fmax(dred[tid], dred[tid + s]);
            __syncthreads();
        }
        double mx = dred[0];
        __syncthreads();
        double e = (c < N) ? exp(lgv - mx) : 0.0;
        dred[tid] = e;
        __syncthreads();
        for (int s = 128; s; s >>= 1) {
            if (tid < s) dred[tid] += dred[tid + s];
            __syncthreads();
        }
        double se = dred[0];
        __syncthreads();
        float p = (c < N) ? (float)(e / se) : -1.f;

        for (int kk = 0; kk < k; kk++) {
            pred[tid] = p;
            ired[tid] = (c < N) ? c : (1 << 20);
            __syncthreads();
            for (int s = 128; s; s >>= 1) {
                if (tid < s) {
                    float ov = pred[tid + s]; int oi = ired[tid + s];
                    if (ov > pred[tid] || (ov == pred[tid] && oi < ired[tid])) {
                        pred[tid] = ov; ired[tid] = oi;
                    }
                }
                __syncthreads();
            }
            if (tid == 0) {
                sout[b * stride + soff + kk] = pred[0];
                iout[b * stride + soff + kk] = ired[0];
            }
            int win = ired[0];
            __syncthreads();
            if (c == win) p = -1.f;
        }
    }
}

// joint scores: f32 left-assoc product chain, stable desc argsort, [15,5] ints
__global__ void finalize_q(const float* __restrict__ s0, const float* __restrict__ s1,
                           const float* __restrict__ s2, const float* __restrict__ s3,
                           const float* __restrict__ s4,
                           const int* __restrict__ i0, const int* __restrict__ i1,
                           const int* __restrict__ i2, const int* __restrict__ i3,
                           const int* __restrict__ i4,
                           int* __restrict__ out)
{
    int b = blockIdx.x * 256 + threadIdx.x;
    float sc[15];
    float a0 = s0[b];
    for (int t = 0; t < 15; t++) {
        int a = t / 5;
        float v = a0 * s1[b * 3 + a];
        v = v * s2[b * 3 + a];
        v = v * s3[b * 15 + t];
        v = v * s4[b * 15 + t];
        sc[t] = v;
    }
    bool used[15] = {false};
    for (int r = 0; r < 15; r++) {
        int best = -1; float bv = -INFINITY;
        for (int t = 0; t < 15; t++)
            if (!used[t] && sc[t] > bv) { bv = sc[t]; best = t; }
        used[best] = true;
        int a = best / 5;
        int* o = out + (size_t)b * 75 + r * 5;
        o[0] = i0[b];
        o[1] = i1[b * 3 + a];
        o[2] = i2[b * 3 + a];
        o[3] = i3[b * 15 + best];
        o[4] = i4[b * 15 + best];
    }
}

// ===========================================================================
// Persistent cooperative stage-4: 48 phases, one launch.
// ===========================================================================
union SM {
    struct { double Al[16][129]; double Bl[16][128]; int idc[2][128]; } g;
    struct { double h2s[8][1024]; double dred[256]; float pred[256]; int ired[256]; } t;
};

struct S4Args {
    const double* bufC; double* base; double* h1; double* h2;
    const float* W4a; const float* W4b;          // Wh1(4)+1280*1024, +1792*1024
    const float* bh1_4; const float* Wh2_4; const float* bh2_4;
    const float* Wo4; const float* bo4;
    const float* Ws1; const float* bs1; const float* Ws2; const float* bs2;
    const float* Wr;  const float* br;
    const int* i1; const int* i2; const int* i3;
    float* s4; int* i4;
    unsigned* bar;       // [0]=cnt, [1]=gen (memset to 0 pre-launch)
    int nblk;
};

__device__ __forceinline__ void grid_bar(unsigned* bar, int nblk)
{
    __threadfence();
    __syncthreads();
    if (threadIdx.x == 0) {
        unsigned g = __atomic_load_n(&bar[1], __ATOMIC_ACQUIRE);
        unsigned v = __atomic_add_fetch(&bar[0], 1u, __ATOMIC_ACQ_REL);
        if (v == (unsigned)nblk) {
            __atomic_store_n(&bar[0], 0u, __ATOMIC_RELAXED);
            __atomic_store_n(&bar[1], g + 1u, __ATOMIC_RELEASE);
        } else {
            while (__atomic_load_n(&bar[1], __ATOMIC_ACQUIRE) == g)
                __builtin_amdgcn_s_sleep(8);
        }
    }
    __syncthreads();
    __threadfence();
}

// GEMM phase: AHEAD=true -> pure f64 A (KA==K); else pure gather segments.
template<int ACT, bool HB, bool HA, int NS, bool AHEAD>
__device__ __forceinline__ void gphase(SM* sm,
    const double* __restrict__ A,
    const float* __restrict__ W,
    const float* __restrict__ bias,
    const double* __restrict__ addsrc,
    double* __restrict__ C, int K,
    GSet g0, GSet g1)
{
    const int tid  = threadIdx.x;
    const int lane = tid & 63;
    const int w    = tid >> 6;
    const int q    = lane >> 4;
    const int c    = lane & 15;
    const int m0w  = (w >> 1) * 64;
    const int n0w  = (w & 1) * 64;
    const size_t m0 = (size_t)(blockIdx.x >> 3) * 128;
    const int    n0 = (blockIdx.x & 7) * 128;

    const int srow = tid >> 1;
    const int half = tid & 1;
    const int bk   = tid >> 4;
    const int bseg = tid & 15;

    if (!AHEAD) {
        if (NS > 0 && tid < 128)
            sm->g.idc[0][tid] = g0.idx[(size_t)(m0 + tid) * g0.is + g0.io];
        if (NS > 1 && tid >= 128)
            sm->g.idc[1][tid - 128] = g1.idx[(size_t)(m0 + tid - 128) * g1.is + g1.io];
    }

    d4_t acc[4][4];
#pragma unroll
    for (int i = 0; i < 4; i++)
#pragma unroll
        for (int j = 0; j < 4; j++) acc[i][j] = (d4_t){0.0, 0.0, 0.0, 0.0};

    if (!AHEAD) __syncthreads();

    for (int kt = 0; kt < K; kt += 16) {
        if (AHEAD) {
            const double* ap = A + (m0 + srow) * 1024 + kt + half * 8;
#pragma unroll
            for (int e = 0; e < 8; e++)
                sm->g.Al[half * 8 + e][srow] = ap[e];
        } else {
            const int koff = kt + half * 8;
            const int s = koff >> 8;
            const int lk = koff & 255;
            const GSet& g = (NS > 1 && s) ? g1 : g0;
            const float* tp = g.T + (size_t)sm->g.idc[s][srow] * 256 + lk;
            const float* bp = g.bT + lk;
#pragma unroll
            for (int e = 0; e < 8; e++) {
                double v = (double)tp[e] + (double)bp[e];
                sm->g.Al[half * 8 + e][srow] = v > 0.0 ? v : 0.0;
            }
        }
        {
            const float* wp = W + (size_t)(kt + bk) * 1024 + n0 + bseg;
#pragma unroll
            for (int e = 0; e < 8; e++)
                sm->g.Bl[bk][bseg + 16 * e] = (double)wp[16 * e];
        }
        __syncthreads();
#pragma unroll
        for (int kk = 0; kk < 4; kk++) {
            double a[4], b[4];
#pragma unroll
            for (int i = 0; i < 4; i++) a[i] = sm->g.Al[kk * 4 + q][m0w + i * 16 + c];
#pragma unroll
            for (int j = 0; j < 4; j++) b[j] = sm->g.Bl[kk * 4 + q][n0w + j * 16 + c];
#pragma unroll
            for (int i = 0; i < 4; i++)
#pragma unroll
                for (int j = 0; j < 4; j++)
                    acc[i][j] = __builtin_amdgcn_mfma_f64_16x16x4f64(
                        a[i], b[j], acc[i][j], 0, 0, 0);
        }
        __syncthreads();
    }

#pragma unroll
    for (int i = 0; i < 4; i++)
#pragma unroll
        for (int j = 0; j < 4; j++)
#pragma unroll
            for (int v = 0; v < 4; v++) {
                size_t gr = m0 + m0w + i * 16 + q * 4 + v;
                int    gc = n0 + n0w + j * 16 + c;
                double val = acc[i][j][v];
                if (HB) val += (double)bias[gc];
                if (HA) val += addsrc[gr * 1024 + gc];
                if (ACT == ACT_RELU) val = val > 0.0 ? val : 0.0;
                if (ACT == ACT_TANH) val = tanh(val);
                C[gr * 1024 + gc] = val;
            }
}

// wo_topk phase: 16 rows/block (two 8-row groups), k=1, N=235, slot t
__device__ __forceinline__ void wophase(SM* sm,
    const double* __restrict__ h2,
    const float* __restrict__ W, const float* __restrict__ bo,
    int N, float* __restrict__ sout, int* __restrict__ iout,
    int stride, int soff)
{
    const int tid = threadIdx.x;
    for (int grp = 0; grp < 2; grp++) {
        const size_t rbase = (size_t)blockIdx.x * 16 + grp * 8;
        for (int t = tid; t < 8192; t += 256)
            sm->t.h2s[t >> 10][t & 1023] = h2[(rbase + (t >> 10)) * 1024 + (t & 1023)];
        __syncthreads();

        const int c = tid;
        double a[8] = {0, 0, 0, 0, 0, 0, 0, 0};
        if (c < N) {
            for (int kk = 0; kk < 1024; kk++) {
                double wv = (double)W[(size_t)kk * N + c];
#pragma unroll
                for (int r = 0; r < 8; r++)
                    a[r] = fma(sm->t.h2s[r][kk], wv, a[r]);
            }
        }
        double bb = (c < N) ? (double)bo[c] : 0.0;

        for (int r = 0; r < 8; r++) {
            size_t b = rbase + r;
            double lgv = a[r] + bb;
            sm->t.dred[tid] = (c < N) ? lgv : -INFINITY;
            __syncthreads();
            for (int s = 128; s; s >>= 1) {
                if (tid < s) sm->t.dred[tid] = fmax(sm->t.dred[tid], sm->t.dred[tid + s]);
                __syncthreads();
            }
            double mx = sm->t.dred[0];
            __syncthreads();
            double e = (c < N) ? exp(lgv - mx) : 0.0;
            sm->t.dred[tid] = e;
            __syncthreads();
            for (int s = 128; s; s >>= 1) {
                if (tid < s) sm->t.dred[tid] += sm->t.dred[tid + s];
                __syncthreads();
            }
            double se = sm->t.dred[0];
            __syncthreads();
            float p = (c < N) ? (float)(e / se) : -1.f;

            sm->t.pred[tid] = p;
            sm->t.ired[tid] = (c < N) ? c : (1 << 20);
            __syncthreads();
            for (int s = 128; s; s >>= 1) {
                if (tid < s) {
                    float ov = sm->t.pred[tid + s]; int oi = sm->t.ired[tid + s];
                    if (ov > sm->t.pred[tid] || (ov == sm->t.pred[tid] && oi < sm->t.ired[tid])) {
                        sm->t.pred[tid] = ov; sm->t.ired[tid] = oi;
                    }
                }
                __syncthreads();
            }
            if (tid == 0) {
                sout[b * stride + soff] = sm->t.pred[0];
                iout[b * stride + soff] = sm->t.ired[0];
            }
            __syncthreads();
        }
        __syncthreads();
    }
}

__global__ __launch_bounds__(256, 2)
void s4persist(S4Args p)
{
    __shared__ SM sm;
    for (int a = 0; a < 3; a++) {
        GSet ga = {p.Ws1, p.bs1, p.i1, 3, a};
        GSet gb = {p.Ws2, p.bs2, p.i2, 3, a};
        gphase<ACT_NONE, false, true, 2, false>(&sm, nullptr, p.W4a, nullptr, p.bufC, p.base, 512, ga, gb);
        grid_bar(p.bar, p.nblk);
        for (int cc = 0; cc < 5; cc++) {
            int t = a * 5 + cc;
            GSet gr_ = {p.Wr, p.br, p.i3, 15, t};
            gphase<ACT_RELU, true, true, 1, false>(&sm, nullptr, p.W4b, p.bh1_4, p.base, p.h1, 256, gr_, gr_);
            grid_bar(p.bar, p.nblk);
            gphase<ACT_TANH, true, false, 0, true>(&sm, p.h1, p.Wh2_4, p.bh2_4, nullptr, p.h2, 1024, gr_, gr_);
            grid_bar(p.bar, p.nblk);
            wophase(&sm, p.h2, p.Wo4, p.bo4, 235, p.s4, p.i4, 15, t);
            grid_bar(p.bar, p.nblk);
        }
    }
}

// ---------------- host-side dispatch ----------------
static const GSet GNULL = {nullptr, nullptr, nullptr, 0, 0};

static void mm(hipStream_t st, int a_is_f32, const void* A, int lda, int KA,
               const float* W, const float* bias,
               const double* add, double* C, int K, int rows,
               GSet g0, GSet g1, int act)
{
    dim3 grid(8, rows / 128);
    int ns = (K - KA) >> 8;
#define LK(TA, AC, HBv, HAv, NSv) hipLaunchKernelGGL((mgemm3<TA, AC, HBv, HAv, NSv>), grid, dim3(256), 0, st, \
        (const TA*)A, lda, KA, W, bias, add, C, K, g0, g1)
#define NSD(TA, AC, HBv, HAv) do { if (ns == 0) LK(TA, AC, HBv, HAv, 0); \
                                   else if (ns == 1) LK(TA, AC, HBv, HAv, 1); \
                                   else LK(TA, AC, HBv, HAv, 2); } while (0)
#define ACTS(TA, HBv, HAv) do { if (act == 0) NSD(TA, 0, HBv, HAv); \
                                else if (act == 1) NSD(TA, 1, HBv, HAv); \
                                else NSD(TA, 2, HBv, HAv); } while (0)
#define BDISP(TA) do { if (bias) { if (add) ACTS(TA, true, true); else ACTS(TA, true, false); } \
                       else      { if (add) ACTS(TA, false, true); else ACTS(TA, false, false); } } while (0)
    if (a_is_f32) BDISP(float); else BDISP(double);
#undef BDISP
#undef ACTS
#undef NSD
#undef LK
}

extern "C" void kernel_launch(void* const* d_in, const int* in_sizes, int n_in,
                              void* d_out, int out_size, void* d_ws, size_t ws_size,
                              hipStream_t stream)
{
    (void)in_sizes; (void)n_in; (void)out_size;
    const float* feat = (const float*)d_in[0];
    const float* Wc  = (const float*)d_in[1];
    const float* bc  = (const float*)d_in[2];
    const float* Ws1 = (const float*)d_in[3];
    const float* bs1 = (const float*)d_in[4];
    const float* Ws2 = (const float*)d_in[5];
    const float* bs2 = (const float*)d_in[6];
    const float* Wr  = (const float*)d_in[7];
    const float* br  = (const float*)d_in[8];
    auto Wh1 = [&](int i) { return (const float*)d_in[9 + 6 * i]; };
    auto bh1 = [&](int i) { return (const float*)d_in[10 + 6 * i]; };
    auto Wh2 = [&](int i) { return (const float*)d_in[11 + 6 * i]; };
    auto bh2 = [&](int i) { return (const float*)d_in[12 + 6 * i]; };
    auto Wo  = [&](int i) { return (const float*)d_in[13 + 6 * i]; };
    auto bo  = [&](int i) { return (const float*)d_in[14 + 6 * i]; };
    const int outs[5] = {54, 87, 87, 235, 235};

    const size_t perRow = 4096ull * 8 + 37ull * 4 + 37ull * 4;
    int R = NB;
    while (R > 1024 && (size_t)R * perRow + 256 > ws_size) R >>= 1;

    double* ws = (double*)d_ws;
    size_t off = 0;
    auto alloc = [&](size_t n) { double* p = ws + off; off += n; return p; };
    double* bufC = alloc((size_t)R * 1024);
    double* base = alloc((size_t)R * 1024);
    double* h1   = alloc((size_t)R * 1024);
    double* h2   = alloc((size_t)R * 1024);
    float* fbase = (float*)(ws + off);
    float* s0 = fbase;            float* s1 = fbase + R;
    float* s2 = s1 + 3 * R;       float* s3 = s2 + 3 * R;
    float* s4 = s3 + 15 * R;
    int* ibase = (int*)(s4 + 15 * R);
    int* i0 = ibase;              int* i1 = ibase + R;
    int* i2 = i1 + 3 * R;         int* i3 = i2 + 3 * R;
    int* i4 = i3 + 15 * R;
    unsigned* bar = (unsigned*)(i4 + 15 * R);

    for (int r0 = 0; r0 < NB; r0 += R) {
        const float* fC = feat + (size_t)r0 * 1024;
        auto WOT = [&](int st, int N, int k, float* so, int* io_, int stride, int soff) {
            hipLaunchKernelGGL(wo_topk, dim3(R / 8), dim3(256), 0, stream,
                               h2, Wo(st), bo(st), N, k, so, io_, stride, soff);
        };

        // ---- stage 0 (K=1024) ----
        mm(stream, 1, fC, 1024, 1024, Wh1(0), bh1(0), nullptr, h1, 1024, R, GNULL, GNULL, ACT_RELU);
        mm(stream, 0, h1, 1024, 1024, Wh2(0), bh2(0), nullptr, h2, 1024, R, GNULL, GNULL, ACT_TANH);
        WOT(0, outs[0], 1, s0, i0, 1, 0);

        GSet gm0 = {Wc, bc, i0, 1, 0};

        // ---- stage 1 (K=1280 fused feat+msg0 gather) ----
        mm(stream, 1, fC, 1024, 1024, Wh1(1), bh1(1), nullptr, h1, 1280, R, gm0, GNULL, ACT_RELU);
        mm(stream, 0, h1, 1024, 1024, Wh2(1), bh2(1), nullptr, h2, 1024, R, GNULL, GNULL, ACT_TANH);
        WOT(1, outs[1], 3, s1, i1, 3, 0);

        // ---- stage 2 (per-beam) ----
        mm(stream, 1, fC, 1024, 1024, Wh1(2), nullptr, nullptr, bufC, 1280, R, gm0, GNULL, ACT_NONE);
        for (int a = 0; a < 3; a++) {
            GSet g = {Ws1, bs1, i1, 3, a};
            mm(stream, 1, nullptr, 0, 0, Wh1(2) + (size_t)1280 * 1024, bh1(2), bufC, h1, 256, R, g, GNULL, ACT_RELU);
            mm(stream, 0, h1, 1024, 1024, Wh2(2), bh2(2), nullptr, h2, 1024, R, GNULL, GNULL, ACT_TANH);
            WOT(2, outs[2], 1, s2, i2, 3, a);
        }

        // ---- stage 3 (per-beam) ----
        mm(stream, 1, fC, 1024, 1024, Wh1(3), nullptr, nullptr, bufC, 1280, R, gm0, GNULL, ACT_NONE);
        for (int a = 0; a < 3; a++) {
            GSet ga = {Ws1, bs1, i1, 3, a};
            GSet gb = {Ws2, bs2, i2, 3, a};
            mm(stream, 1, nullptr, 0, 0, Wh1(3) + (size_t)1280 * 1024, bh1(3), bufC, h1, 512, R, ga, gb, ACT_RELU);
            mm(stream, 0, h1, 1024, 1024, Wh2(3), bh2(3), nullptr, h2, 1024, R, GNULL, GNULL, ACT_TANH);
            WOT(3, outs[3], 5, s3, i3, 15, 5 * a);
        }

        // ---- stage 4: persistent cooperative (fallback: launch loop) ----
        mm(stream, 1, fC, 1024, 1024, Wh1(4), nullptr, nullptr, bufC, 1280, R, gm0, GNULL, ACT_NONE);
        {
            hipMemsetAsync(bar, 0, 128, stream);
            S4Args args = {bufC, base, h1, h2,
                           Wh1(4) + (size_t)1280 * 1024, Wh1(4) + (size_t)1792 * 1024,
                           bh1(4), Wh2(4), bh2(4), Wo(4), bo(4),
                           Ws1, bs1, Ws2, bs2, Wr, br,
                           i1, i2, i3, s4, i4, bar, 8 * (R / 128)};
            void* kp[] = {&args};
            hipError_t ce = hipLaunchCooperativeKernel((void*)s4persist,
                                dim3(8 * (R / 128)), dim3(256), kp, 0, stream);
            if (ce != hipSuccess) {
                for (int a = 0; a < 3; a++) {
                    GSet ga = {Ws1, bs1, i1, 3, a};
                    GSet gb = {Ws2, bs2, i2, 3, a};
                    mm(stream, 1, nullptr, 0, 0, Wh1(4) + (size_t)1280 * 1024, nullptr, bufC, base, 512, R, ga, gb, ACT_NONE);
                    for (int cc = 0; cc < 5; cc++) {
                        int t = a * 5 + cc;
                        GSet gr_ = {Wr, br, i3, 15, t};
                        mm(stream, 1, nullptr, 0, 0, Wh1(4) + (size_t)1792 * 1024, bh1(4), base, h1, 256, R, gr_, GNULL, ACT_RELU);
                        mm(stream, 0, h1, 1024, 1024, Wh2(4), bh2(4), nullptr, h2, 1024, R, GNULL, GNULL, ACT_TANH);
                        WOT(4, outs[4], 1, s4, i4, 15, t);
                    }
                }
            }
        }

        // ---- final join + stable descending argsort on f32 products ----
        hipLaunchKernelGGL(finalize_q, dim3(R / 256), dim3(256), 0, stream,
                           s0, s1, s2, s3, s4, i0, i1, i2, i3, i4, (int*)d_out + (size_t)r0 * 75);
    }
}

// Round 13
// 21532.433 us; speedup vs baseline: 2.0369x; 2.0369x over previous
//
#include <hip/hip_runtime.h>
#include <math.h>

#define NB 8192
enum { ACT_NONE = 0, ACT_RELU = 1, ACT_TANH = 2 };

typedef double d4_t __attribute__((ext_vector_type(4)));

struct GSet {            // gathered-message A-segment: relu(T[idx]+bT), 256 wide
    const float* T;
    const float* bT;
    const int*   idx;
    int is, io;          // id = idx[b*is + io]
};

// ---------------------------------------------------------------------------
// f64 MFMA GEMM, r8 tile (BK=16, zero-conflict staging, ~69 TF measured).
// NS = compile-time count of gathered 256-wide A-segments appended after the
// KA head columns; NS=0 is the branch-free r8 body (hot path).
// Tile 128x128, 256 thr = 4 waves (2x2 of 64x64), v_mfma_f64_16x16x4_f64.
// Per-element: single f64 MFMA chain, k ascending — decision-grade (~1e-15);
// decisions stay f32-quantized + stable-tie downstream.
// ---------------------------------------------------------------------------
template<typename TA, int ACT, bool HB, bool HA, int NS>
__global__ __launch_bounds__(256)
void mgemm3(const TA* __restrict__ A, int lda, int KA,
            const float* __restrict__ W,
            const float* __restrict__ bias,
            const double* __restrict__ addsrc,
            double* __restrict__ C, int K,
            GSet g0, GSet g1)
{
    __shared__ double Al[16][129];
    __shared__ double Bl[16][128];
    __shared__ int idc[2][128];
    const int tid  = threadIdx.x;
    const int lane = tid & 63;
    const int w    = tid >> 6;
    const int q    = lane >> 4;
    const int c    = lane & 15;
    const int m0w  = (w >> 1) * 64;
    const int n0w  = (w & 1) * 64;
    const size_t m0 = (size_t)blockIdx.y * 128;
    const int    n0 = blockIdx.x * 128;

    const int srow = tid >> 1;        // A-stage: row 0..127 (r8 pattern)
    const int half = tid & 1;         // A-stage: 8-elem k-half
    const int bk   = tid >> 4;        // B-stage: k-row 0..15 (r8 pattern)
    const int bseg = tid & 15;        // B-stage: col seg, stride-16 stores

    if (NS > 0 && tid < 128)
        idc[0][tid] = g0.idx[(size_t)(m0 + tid) * g0.is + g0.io];
    if (NS > 1 && tid >= 128)
        idc[1][tid - 128] = g1.idx[(size_t)(m0 + tid - 128) * g1.is + g1.io];

    d4_t acc[4][4];
#pragma unroll
    for (int i = 0; i < 4; i++)
#pragma unroll
        for (int j = 0; j < 4; j++) acc[i][j] = (d4_t){0.0, 0.0, 0.0, 0.0};

    if (NS > 0) __syncthreads();

    for (int kt = 0; kt < K; kt += 16) {
        if (NS == 0) {
            const TA* ap = A + (m0 + srow) * (size_t)lda + kt + half * 8;
#pragma unroll
            for (int e = 0; e < 8; e++)
                Al[half * 8 + e][srow] = (double)ap[e];
        } else {
            const int kb = kt + half * 8;
            if (kb < KA) {
                const TA* ap = A + (m0 + srow) * (size_t)lda + kb;
#pragma unroll
                for (int e = 0; e < 8; e++)
                    Al[half * 8 + e][srow] = (double)ap[e];
            } else {
                const int koff = kb - KA;
                const int s = koff >> 8;
                const int lk = koff & 255;
                const GSet& g = s ? g1 : g0;
                const float* tp = g.T + (size_t)idc[s][srow] * 256 + lk;
                const float* bp = g.bT + lk;
#pragma unroll
                for (int e = 0; e < 8; e++) {
                    double v = (double)tp[e] + (double)bp[e];
                    Al[half * 8 + e][srow] = v > 0.0 ? v : 0.0;
                }
            }
        }
        {
            const float* wp = W + (size_t)(kt + bk) * 1024 + n0 + bseg;
#pragma unroll
            for (int e = 0; e < 8; e++)
                Bl[bk][bseg + 16 * e] = (double)wp[16 * e];
        }
        __syncthreads();
#pragma unroll
        for (int kk = 0; kk < 4; kk++) {
            double a[4], b[4];
#pragma unroll
            for (int i = 0; i < 4; i++) a[i] = Al[kk * 4 + q][m0w + i * 16 + c];
#pragma unroll
            for (int j = 0; j < 4; j++) b[j] = Bl[kk * 4 + q][n0w + j * 16 + c];
#pragma unroll
            for (int i = 0; i < 4; i++)
#pragma unroll
                for (int j = 0; j < 4; j++)
                    acc[i][j] = __builtin_amdgcn_mfma_f64_16x16x4f64(
                        a[i], b[j], acc[i][j], 0, 0, 0);
        }
        __syncthreads();
    }

#pragma unroll
    for (int i = 0; i < 4; i++)
#pragma unroll
        for (int j = 0; j < 4; j++)
#pragma unroll
            for (int v = 0; v < 4; v++) {
                size_t gr = m0 + m0w + i * 16 + q * 4 + v;
                int    gc = n0 + n0w + j * 16 + c;
                double val = acc[i][j][v];
                if (HB) val += (double)bias[gc];
                if (HA) val += addsrc[gr * 1024 + gc];
                if (ACT == ACT_RELU) val = val > 0.0 ? val : 0.0;
                if (ACT == ACT_TANH) val = tanh(val);
                C[gr * 1024 + gc] = val;
            }
}

// ---------------------------------------------------------------------------
// Fused Wo-GEMV + f64 softmax + f32-quantized stable top-k. 8 rows/block.
// ---------------------------------------------------------------------------
__global__ __launch_bounds__(256)
void wo_topk(const double* __restrict__ h2,
             const float* __restrict__ W, const float* __restrict__ bo,
             int N, int k,
             float* __restrict__ sout, int* __restrict__ iout,
             int stride, int soff)
{
    __shared__ double h2s[8][1024];
    __shared__ double dred[256];
    __shared__ float  pred[256];
    __shared__ int    ired[256];
    const int tid = threadIdx.x;
    const size_t rbase = (size_t)blockIdx.x * 8;

    for (int t = tid; t < 8192; t += 256)
        h2s[t >> 10][t & 1023] = h2[(rbase + (t >> 10)) * 1024 + (t & 1023)];
    __syncthreads();

    const int c = tid;
    double a[8] = {0, 0, 0, 0, 0, 0, 0, 0};
    if (c < N) {
        for (int kk = 0; kk < 1024; kk++) {
            double wv = (double)W[(size_t)kk * N + c];
#pragma unroll
            for (int r = 0; r < 8; r++)
                a[r] = fma(h2s[r][kk], wv, a[r]);
        }
    }
    double bb = (c < N) ? (double)bo[c] : 0.0;

    for (int r = 0; r < 8; r++) {
        size_t b = rbase + r;
        double lgv = a[r] + bb;
        dred[tid] = (c < N) ? lgv : -INFINITY;
        __syncthreads();
        for (int s = 128; s; s >>= 1) {
            if (tid < s) dred[tid] = fmax(dred[tid], dred[tid + s]);
            __syncthreads();
        }
        double mx = dred[0];
        __syncthreads();
        double e = (c < N) ? exp(lgv - mx) : 0.0;
        dred[tid] = e;
        __syncthreads();
        for (int s = 128; s; s >>= 1) {
            if (tid < s) dred[tid] += dred[tid + s];
            __syncthreads();
        }
        double se = dred[0];
        __syncthreads();
        float p = (c < N) ? (float)(e / se) : -1.f;

        for (int kk = 0; kk < k; kk++) {
            pred[tid] = p;
            ired[tid] = (c < N) ? c : (1 << 20);
            __syncthreads();
            for (int s = 128; s; s >>= 1) {
                if (tid < s) {
                    float ov = pred[tid + s]; int oi = ired[tid + s];
                    if (ov > pred[tid] || (ov == pred[tid] && oi < ired[tid])) {
                        pred[tid] = ov; ired[tid] = oi;
                    }
                }
                __syncthreads();
            }
            if (tid == 0) {
                sout[b * stride + soff + kk] = pred[0];
                iout[b * stride + soff + kk] = ired[0];
            }
            int win = ired[0];
            __syncthreads();
            if (c == win) p = -1.f;
        }
    }
}

// joint scores: f32 left-assoc product chain, stable desc argsort, [15,5] ints
__global__ void finalize_q(const float* __restrict__ s0, const float* __restrict__ s1,
                           const float* __restrict__ s2, const float* __restrict__ s3,
                           const float* __restrict__ s4,
                           const int* __restrict__ i0, const int* __restrict__ i1,
                           const int* __restrict__ i2, const int* __restrict__ i3,
                           const int* __restrict__ i4,
                           int* __restrict__ out)
{
    int b = blockIdx.x * 256 + threadIdx.x;
    float sc[15];
    float a0 = s0[b];
    for (int t = 0; t < 15; t++) {
        int a = t / 5;
        float v = a0 * s1[b * 3 + a];
        v = v * s2[b * 3 + a];
        v = v * s3[b * 15 + t];
        v = v * s4[b * 15 + t];
        sc[t] = v;
    }
    bool used[15] = {false};
    for (int r = 0; r < 15; r++) {
        int best = -1; float bv = -INFINITY;
        for (int t = 0; t < 15; t++)
            if (!used[t] && sc[t] > bv) { bv = sc[t]; best = t; }
        used[best] = true;
        int a = best / 5;
        int* o = out + (size_t)b * 75 + r * 5;
        o[0] = i0[b];
        o[1] = i1[b * 3 + a];
        o[2] = i2[b * 3 + a];
        o[3] = i3[b * 15 + best];
        o[4] = i4[b * 15 + best];
    }
}

// ---------------- host-side dispatch ----------------
static const GSet GNULL = {nullptr, nullptr, nullptr, 0, 0};

static void mm(hipStream_t st, int a_is_f32, const void* A, int lda, int KA,
               const float* W, const float* bias,
               const double* add, double* C, int K, int rows,
               GSet g0, GSet g1, int act)
{
    dim3 grid(8, rows / 128);
    int ns = (K - KA) >> 8;
#define LK(TA, AC, HBv, HAv, NSv) hipLaunchKernelGGL((mgemm3<TA, AC, HBv, HAv, NSv>), grid, dim3(256), 0, st, \
        (const TA*)A, lda, KA, W, bias, add, C, K, g0, g1)
#define NSD(TA, AC, HBv, HAv) do { if (ns == 0) LK(TA, AC, HBv, HAv, 0); \
                                   else if (ns == 1) LK(TA, AC, HBv, HAv, 1); \
                                   else LK(TA, AC, HBv, HAv, 2); } while (0)
#define ACTS(TA, HBv, HAv) do { if (act == 0) NSD(TA, 0, HBv, HAv); \
                                else if (act == 1) NSD(TA, 1, HBv, HAv); \
                                else NSD(TA, 2, HBv, HAv); } while (0)
#define BDISP(TA) do { if (bias) { if (add) ACTS(TA, true, true); else ACTS(TA, true, false); } \
                       else      { if (add) ACTS(TA, false, true); else ACTS(TA, false, false); } } while (0)
    if (a_is_f32) BDISP(float); else BDISP(double);
#undef BDISP
#undef ACTS
#undef NSD
#undef LK
}

extern "C" void kernel_launch(void* const* d_in, const int* in_sizes, int n_in,
                              void* d_out, int out_size, void* d_ws, size_t ws_size,
                              hipStream_t stream)
{
    (void)in_sizes; (void)n_in; (void)out_size;
    const float* feat = (const float*)d_in[0];
    const float* Wc  = (const float*)d_in[1];
    const float* bc  = (const float*)d_in[2];
    const float* Ws1 = (const float*)d_in[3];
    const float* bs1 = (const float*)d_in[4];
    const float* Ws2 = (const float*)d_in[5];
    const float* bs2 = (const float*)d_in[6];
    const float* Wr  = (const float*)d_in[7];
    const float* br  = (const float*)d_in[8];
    auto Wh1 = [&](int i) { return (const float*)d_in[9 + 6 * i]; };
    auto bh1 = [&](int i) { return (const float*)d_in[10 + 6 * i]; };
    auto Wh2 = [&](int i) { return (const float*)d_in[11 + 6 * i]; };
    auto bh2 = [&](int i) { return (const float*)d_in[12 + 6 * i]; };
    auto Wo  = [&](int i) { return (const float*)d_in[13 + 6 * i]; };
    auto bo  = [&](int i) { return (const float*)d_in[14 + 6 * i]; };
    const int outs[5] = {54, 87, 87, 235, 235};

    const size_t perRow = 4096ull * 8 + 37ull * 4 + 37ull * 4;
    int R = NB;
    while (R > 1024 && (size_t)R * perRow > ws_size) R >>= 1;

    double* ws = (double*)d_ws;
    size_t off = 0;
    auto alloc = [&](size_t n) { double* p = ws + off; off += n; return p; };
    double* bufC = alloc((size_t)R * 1024);
    double* base = alloc((size_t)R * 1024);
    double* h1   = alloc((size_t)R * 1024);
    double* h2   = alloc((size_t)R * 1024);
    float* fbase = (float*)(ws + off);
    float* s0 = fbase;            float* s1 = fbase + R;
    float* s2 = s1 + 3 * R;       float* s3 = s2 + 3 * R;
    float* s4 = s3 + 15 * R;
    int* ibase = (int*)(s4 + 15 * R);
    int* i0 = ibase;              int* i1 = ibase + R;
    int* i2 = i1 + 3 * R;         int* i3 = i2 + 3 * R;
    int* i4 = i3 + 15 * R;

    for (int r0 = 0; r0 < NB; r0 += R) {
        const float* fC = feat + (size_t)r0 * 1024;
        auto WOT = [&](int st, int N, int k, float* so, int* io_, int stride, int soff) {
            hipLaunchKernelGGL(wo_topk, dim3(R / 8), dim3(256), 0, stream,
                               h2, Wo(st), bo(st), N, k, so, io_, stride, soff);
        };

        // ---- stage 0 (K=1024, branch-free NS=0 path) ----
        mm(stream, 1, fC, 1024, 1024, Wh1(0), bh1(0), nullptr, h1, 1024, R, GNULL, GNULL, ACT_RELU);
        mm(stream, 0, h1, 1024, 1024, Wh2(0), bh2(0), nullptr, h2, 1024, R, GNULL, GNULL, ACT_TANH);
        WOT(0, outs[0], 1, s0, i0, 1, 0);

        GSet gm0 = {Wc, bc, i0, 1, 0};

        // ---- stage 1 (K=1280 fused feat+msg0 gather, NS=1) ----
        mm(stream, 1, fC, 1024, 1024, Wh1(1), bh1(1), nullptr, h1, 1280, R, gm0, GNULL, ACT_RELU);
        mm(stream, 0, h1, 1024, 1024, Wh2(1), bh2(1), nullptr, h2, 1024, R, GNULL, GNULL, ACT_TANH);
        WOT(1, outs[1], 3, s1, i1, 3, 0);

        // ---- stage 2 (per-beam) ----
        mm(stream, 1, fC, 1024, 1024, Wh1(2), nullptr, nullptr, bufC, 1280, R, gm0, GNULL, ACT_NONE);
        for (int a = 0; a < 3; a++) {
            GSet g = {Ws1, bs1, i1, 3, a};
            mm(stream, 1, nullptr, 0, 0, Wh1(2) + (size_t)1280 * 1024, bh1(2), bufC, h1, 256, R, g, GNULL, ACT_RELU);
            mm(stream, 0, h1, 1024, 1024, Wh2(2), bh2(2), nullptr, h2, 1024, R, GNULL, GNULL, ACT_TANH);
            WOT(2, outs[2], 1, s2, i2, 3, a);
        }

        // ---- stage 3 (per-beam) ----
        mm(stream, 1, fC, 1024, 1024, Wh1(3), nullptr, nullptr, bufC, 1280, R, gm0, GNULL, ACT_NONE);
        for (int a = 0; a < 3; a++) {
            GSet ga = {Ws1, bs1, i1, 3, a};
            GSet gb = {Ws2, bs2, i2, 3, a};
            mm(stream, 1, nullptr, 0, 0, Wh1(3) + (size_t)1280 * 1024, bh1(3), bufC, h1, 512, R, ga, gb, ACT_RELU);
            mm(stream, 0, h1, 1024, 1024, Wh2(3), bh2(3), nullptr, h2, 1024, R, GNULL, GNULL, ACT_TANH);
            WOT(3, outs[3], 5, s3, i3, 15, 5 * a);
        }

        // ---- stage 4 (per-beam, inner per-c) ----
        mm(stream, 1, fC, 1024, 1024, Wh1(4), nullptr, nullptr, bufC, 1280, R, gm0, GNULL, ACT_NONE);
        for (int a = 0; a < 3; a++) {
            GSet ga = {Ws1, bs1, i1, 3, a};
            GSet gb = {Ws2, bs2, i2, 3, a};
            mm(stream, 1, nullptr, 0, 0, Wh1(4) + (size_t)1280 * 1024, nullptr, bufC, base, 512, R, ga, gb, ACT_NONE);
            for (int cc = 0; cc < 5; cc++) {
                int t = a * 5 + cc;
                GSet gr_ = {Wr, br, i3, 15, t};
                mm(stream, 1, nullptr, 0, 0, Wh1(4) + (size_t)1792 * 1024, bh1(4), base, h1, 256, R, gr_, GNULL, ACT_RELU);
                mm(stream, 0, h1, 1024, 1024, Wh2(4), bh2(4), nullptr, h2, 1024, R, GNULL, GNULL, ACT_TANH);
                WOT(4, outs[4], 1, s4, i4, 15, t);
            }
        }

        // ---- final join + stable descending argsort on f32 products ----
        hipLaunchKernelGGL(finalize_q, dim3(R / 256), dim3(256), 0, stream,
                           s0, s1, s2, s3, s4, i0, i1, i2, i3, i4, (int*)d_out + (size_t)r0 * 75);
    }
}